// Round 11
// baseline (64.922 us; speedup 1.0000x reference)
//
#include <hip/hip_runtime.h>
#include <hip/hip_bf16.h>

#define NBATCH 4
#define NNODE  20000
#define NF     128
#define NK     16
#define NROWS  (NBATCH * NNODE)   // 80000
#define NBLK_G 5000               // gemm blocks, 16 rows each
#define NBLK_F 5000               // finish blocks, 16 rows each
#define WTF_BYTES 65536           // 16t x 4s x 64lane x 16B weight frags (N=256 stacked)
#define BIAS_OFF  WTF_BYTES
#define S_OFF     (WTF_BYTES + 1024)          // bf16 s = x*Ws + b  (20.48 MB)
#define Y_OFF     (S_OFF + NROWS * NF * 2)    // fp8  y = x*Wn      (10.24 MB)

typedef __attribute__((ext_vector_type(8))) short bf16x8_t;
typedef __attribute__((ext_vector_type(4))) float f32x4_t;
typedef __attribute__((ext_vector_type(2))) float f32x2_t;

__device__ __forceinline__ unsigned int f2bf(float f) {
  unsigned int u = __float_as_uint(f);
  u += 0x7fffu + ((u >> 16) & 1u);
  return u >> 16;
}

__device__ __forceinline__ int xcd_swz8(int orig, int nblk) {
  // nblk divisible by 8: chunked bijective swizzle
  return (orig & 7) * (nblk >> 3) + (orig >> 3);
}

// ---------------- K1: weight fragments (N=256 stacked, K=128) + bias -----
__global__ __launch_bounds__(256) void sage_wprep(
    const float* __restrict__ Ws, const float* __restrict__ bs,
    const float* __restrict__ Wn, const float* __restrict__ bn,
    unsigned char* __restrict__ ws)
{
  const int bid = blockIdx.x, tid = threadIdx.x;
  if (bid == 16) {
    if (tid < NF) ((float*)(ws + BIAS_OFF))[tid] = bs[tid] + bn[tid];
    return;
  }
  const int ft = bid * 256 + tid;       // 0..4095
  const int gc = ft >> 8;               // col tile 0..15
  const int s  = (ft >> 6) & 3;         // k-step 0..3 (K=128)
  const int l  = ft & 63;
  const int colg = gc * 16 + (l & 15);  // 0..255 stacked N
  const int k0 = s * 32 + ((l >> 4) << 3);
  const float* W = (colg < NF) ? Ws : Wn;
  const int col = (colg < NF) ? colg : colg - NF;
  unsigned int w[4];
#pragma unroll
  for (int jj = 0; jj < 4; ++jj) {
    const float va = W[(k0 + 2 * jj) * NF + col];
    const float vb = W[(k0 + 2 * jj + 1) * NF + col];
    w[jj] = f2bf(va) | (f2bf(vb) << 16);
  }
  *reinterpret_cast<uint4*>(ws + (size_t)ft * 16) = make_uint4(w[0], w[1], w[2], w[3]);
}

// ---------------- K2: dense GEMM, register-resident weights --------------
// wave wid owns col-tiles 4*wid..4*wid+3 (16 frags = 64 VGPR, loaded once).
// operand-swapped mfma(W, x): lane owns row (lane&15), 4 consecutive cols
// (q*4+reg) per tile -> packed stores. No LDS, no barriers.
__global__ __launch_bounds__(256, 3) void sage_gemm(
    const float* __restrict__ x, unsigned char* __restrict__ ws)
{
  const int tid = threadIdx.x, lane = tid & 63, wid = tid >> 6;
  const int bid = xcd_swz8(blockIdx.x, NBLK_G);
  const int fl = lane & 15, q = lane >> 4;
  const int myrow = bid * 16 + fl;

  const bf16x8_t* wtf = reinterpret_cast<const bf16x8_t*>(ws);
  const float* bias = reinterpret_cast<const float*>(ws + BIAS_OFF);

  // ---- issue ALL loads first, distinct destinations, no uses in between
  bf16x8_t wf[16];
#pragma unroll
  for (int t4 = 0; t4 < 4; ++t4)
#pragma unroll
    for (int s = 0; s < 4; ++s)
      wf[t4 * 4 + s] = wtf[((wid * 4 + t4) * 4 + s) * 64 + lane];

  const float* xr = x + (size_t)myrow * NF;
  float4 xv[8];
#pragma unroll
  for (int s = 0; s < 4; ++s) {
    xv[2 * s]     = *reinterpret_cast<const float4*>(xr + s * 32 + q * 8);
    xv[2 * s + 1] = *reinterpret_cast<const float4*>(xr + s * 32 + q * 8 + 4);
  }

  float4 bv[4] = {};
  if (wid < 2) {
#pragma unroll
    for (int t4 = 0; t4 < 4; ++t4)
      bv[t4] = *reinterpret_cast<const float4*>(
          bias + (wid * 4 + t4) * 16 + q * 4);
  }
  __builtin_amdgcn_sched_barrier(0);   // pin: all loads issued before any use

  // ---- convert x to bf16 B-fragments
  bf16x8_t bx[4];
#pragma unroll
  for (int s = 0; s < 4; ++s) {
    union { unsigned int u[4]; bf16x8_t v; } r;
    r.u[0] = f2bf(xv[2 * s].x) | (f2bf(xv[2 * s].y) << 16);
    r.u[1] = f2bf(xv[2 * s].z) | (f2bf(xv[2 * s].w) << 16);
    r.u[2] = f2bf(xv[2 * s + 1].x) | (f2bf(xv[2 * s + 1].y) << 16);
    r.u[3] = f2bf(xv[2 * s + 1].z) | (f2bf(xv[2 * s + 1].w) << 16);
    bx[s] = r.v;
  }

  // ---- 16 MFMA
  f32x4_t acc[4];
#pragma unroll
  for (int t4 = 0; t4 < 4; ++t4) acc[t4] = (f32x4_t){0.f, 0.f, 0.f, 0.f};
#pragma unroll
  for (int t4 = 0; t4 < 4; ++t4)
#pragma unroll
    for (int s = 0; s < 4; ++s)
      acc[t4] = __builtin_amdgcn_mfma_f32_16x16x32_bf16(
          wf[t4 * 4 + s], bx[s], acc[t4], 0, 0, 0);

  // ---- packed stores
  if (wid < 2) {
    unsigned short* sp = reinterpret_cast<unsigned short*>(ws + S_OFF);
#pragma unroll
    for (int t4 = 0; t4 < 4; ++t4) {
      const int c4 = (wid * 4 + t4) * 16 + q * 4;
      uint2 p;
      p.x = f2bf(acc[t4][0] + bv[t4].x) | (f2bf(acc[t4][1] + bv[t4].y) << 16);
      p.y = f2bf(acc[t4][2] + bv[t4].z) | (f2bf(acc[t4][3] + bv[t4].w) << 16);
      *reinterpret_cast<uint2*>(sp + (size_t)myrow * NF + c4) = p;
    }
  } else {
    unsigned char* yp = ws + Y_OFF;
#pragma unroll
    for (int t4 = 0; t4 < 4; ++t4) {
      const int c4 = ((wid - 2) * 4 + t4) * 16 + q * 4;
      int w8 = __builtin_amdgcn_cvt_pk_fp8_f32(acc[t4][0], acc[t4][1], 0, false);
      w8 = __builtin_amdgcn_cvt_pk_fp8_f32(acc[t4][2], acc[t4][3], w8, true);
      *reinterpret_cast<unsigned int*>(yp + (size_t)myrow * NF + c4) =
          (unsigned int)w8;
    }
  }
}

// ---------------- K3: out = relu(s + mean_k y[idx_k]), 16-deep MLP -------
__global__ __launch_bounds__(256) void sage_fin(
    const unsigned char* __restrict__ ws, const int* __restrict__ adj,
    float* __restrict__ out)
{
  const int tid = threadIdx.x, lane = tid & 63, wid = tid >> 6;
  const int bid = xcd_swz8(blockIdx.x, NBLK_F);
  const int rg = lane >> 4, fl = lane & 15;   // 4 rows/wave, 16 lanes/row
  const int row = bid * 16 + wid * 4 + rg;
  const int b = row / NNODE;

  const unsigned short* sp = reinterpret_cast<const unsigned short*>(ws + S_OFF);
  const unsigned char* yb = ws + Y_OFF + (size_t)b * NNODE * NF + fl * 8;

  const int4* a4 = reinterpret_cast<const int4*>(adj + (size_t)row * NK);
  const int4 t0 = a4[0], t1 = a4[1], t2 = a4[2], t3 = a4[3];
  const int idx[16] = {t0.x, t0.y, t0.z, t0.w, t1.x, t1.y, t1.z, t1.w,
                       t2.x, t2.y, t2.z, t2.w, t3.x, t3.y, t3.z, t3.w};

  const uint4 sv = *reinterpret_cast<const uint4*>(sp + (size_t)row * NF + fl * 8);

  uint2 v[16];
#pragma unroll
  for (int k = 0; k < 16; ++k)
    v[k] = *reinterpret_cast<const uint2*>(yb + (size_t)idx[k] * NF);
  __builtin_amdgcn_sched_barrier(0);   // pin: all 16 loads issue before use

  f32x2_t g0 = {0.f, 0.f}, g1 = {0.f, 0.f}, g2 = {0.f, 0.f}, g3 = {0.f, 0.f};
#pragma unroll
  for (int k = 0; k < 16; ++k) {
    g0 += __builtin_amdgcn_cvt_pk_f32_fp8(v[k].x, false);
    g1 += __builtin_amdgcn_cvt_pk_f32_fp8(v[k].x, true);
    g2 += __builtin_amdgcn_cvt_pk_f32_fp8(v[k].y, false);
    g3 += __builtin_amdgcn_cvt_pk_f32_fp8(v[k].y, true);
  }

  float se[8];
  se[0] = __uint_as_float(sv.x << 16); se[1] = __uint_as_float(sv.x & 0xffff0000u);
  se[2] = __uint_as_float(sv.y << 16); se[3] = __uint_as_float(sv.y & 0xffff0000u);
  se[4] = __uint_as_float(sv.z << 16); se[5] = __uint_as_float(sv.z & 0xffff0000u);
  se[6] = __uint_as_float(sv.w << 16); se[7] = __uint_as_float(sv.w & 0xffff0000u);

  const float sc = 1.f / 16.f;
  float4 o0, o1;
  o0.x = fmaxf(se[0] + g0[0] * sc, 0.f);
  o0.y = fmaxf(se[1] + g0[1] * sc, 0.f);
  o0.z = fmaxf(se[2] + g1[0] * sc, 0.f);
  o0.w = fmaxf(se[3] + g1[1] * sc, 0.f);
  o1.x = fmaxf(se[4] + g2[0] * sc, 0.f);
  o1.y = fmaxf(se[5] + g2[1] * sc, 0.f);
  o1.z = fmaxf(se[6] + g3[0] * sc, 0.f);
  o1.w = fmaxf(se[7] + g3[1] * sc, 0.f);
  float* op = out + (size_t)row * NF + fl * 8;
  *reinterpret_cast<float4*>(op)     = o0;
  *reinterpret_cast<float4*>(op + 4) = o1;
}

extern "C" void kernel_launch(void* const* d_in, const int* in_sizes, int n_in,
                              void* d_out, int out_size, void* d_ws, size_t ws_size,
                              hipStream_t stream) {
  const float* x     = (const float*)d_in[0];
  const int*   adj   = (const int*)d_in[1];
  const float* Wself = (const float*)d_in[2];
  const float* bself = (const float*)d_in[3];
  const float* Wnei  = (const float*)d_in[4];
  const float* bnei  = (const float*)d_in[5];
  float* out = (float*)d_out;
  unsigned char* ws = (unsigned char*)d_ws;

  hipLaunchKernelGGL(sage_wprep, dim3(17), dim3(256), 0, stream,
                     Wself, bself, Wnei, bnei, ws);
  hipLaunchKernelGGL(sage_gemm, dim3(NBLK_G), dim3(256), 0, stream, x, ws);
  hipLaunchKernelGGL(sage_fin, dim3(NBLK_F), dim3(256), 0, stream,
                     ws, adj, out);
}

// Round 12
// 52.588 us; speedup vs baseline: 1.2345x; 1.2345x over previous
//
#include <hip/hip_runtime.h>
#include <hip/hip_bf16.h>

#define NBATCH 4
#define NNODE  20000
#define NF     128
#define NK     16
#define NROWS  (NBATCH * NNODE)   // 80000
#define NBLK_G 1250               // gemm blocks, 64 rows each
#define NBLK_F 5000               // finish blocks, 16 rows each
#define WTF_BYTES 65536           // 16t x 4s x 64lane x 16B weight frags (N=256 stacked)
#define BIAS_OFF  WTF_BYTES
#define S_OFF     (WTF_BYTES + 1024)          // bf16 s = x*Ws + b  (20.48 MB)
#define Y_OFF     (S_OFF + NROWS * NF * 2)    // fp8  y = x*Wn      (10.24 MB)

typedef __attribute__((ext_vector_type(8))) short bf16x8_t;
typedef __attribute__((ext_vector_type(4))) float f32x4_t;
typedef __attribute__((ext_vector_type(2))) float f32x2_t;

__device__ __forceinline__ unsigned int f2bf(float f) {
  unsigned int u = __float_as_uint(f);
  u += 0x7fffu + ((u >> 16) & 1u);
  return u >> 16;
}

__device__ __forceinline__ int xcd_swz_g(int orig) {
  // bijective XCD-chunked swizzle, nwg=1250: q=156, r=2
  const int xcd = orig & 7, i = orig >> 3;
  const int q = NBLK_G / 8, r = NBLK_G % 8;
  return (xcd < r ? xcd * (q + 1) : r * (q + 1) + (xcd - r) * q) + i;
}

__device__ __forceinline__ int xcd_swz_f(int orig) {
  return (orig & 7) * (NBLK_F / 8) + (orig >> 3);
}

__device__ __forceinline__ void stage16(const void* g, void* l) {
  __builtin_amdgcn_global_load_lds(
      (const __attribute__((address_space(1))) unsigned int*)g,
      (__attribute__((address_space(3))) unsigned int*)l, 16, 0, 0);
}

// x-tile LDS: [64 rows][256B], XOR-swizzled (write & read sides)
__device__ __forceinline__ int swzx(int row, int kbyte) {
  return (row << 8) + (kbyte ^ ((row & 15) << 4));
}

// ---------------- K1: weight fragments (N=256 stacked, K=128) + bias -----
__global__ __launch_bounds__(256) void sage_wprep(
    const float* __restrict__ Ws, const float* __restrict__ bs,
    const float* __restrict__ Wn, const float* __restrict__ bn,
    unsigned char* __restrict__ ws)
{
  const int bid = blockIdx.x, tid = threadIdx.x;
  if (bid == 16) {
    if (tid < NF) ((float*)(ws + BIAS_OFF))[tid] = bs[tid] + bn[tid];
    return;
  }
  const int ft = bid * 256 + tid;       // 0..4095
  const int gc = ft >> 8;               // col tile 0..15
  const int s  = (ft >> 6) & 3;         // k-step 0..3 (K=128)
  const int l  = ft & 63;
  const int colg = gc * 16 + (l & 15);  // 0..255 stacked N
  const int k0 = s * 32 + ((l >> 4) << 3);
  const float* W = (colg < NF) ? Ws : Wn;
  const int col = (colg < NF) ? colg : colg - NF;
  unsigned int w[4];
#pragma unroll
  for (int jj = 0; jj < 4; ++jj) {
    const float va = W[(k0 + 2 * jj) * NF + col];
    const float vb = W[(k0 + 2 * jj + 1) * NF + col];
    w[jj] = f2bf(va) | (f2bf(vb) << 16);
  }
  *reinterpret_cast<uint4*>(ws + (size_t)ft * 16) = make_uint4(w[0], w[1], w[2], w[3]);
}

// ---------------- K2: dense GEMM, LDS weights + LDS x-tile ---------------
// operand-swapped mfma(Wfrag, xfrag): lane owns row (lane&15) and 4
// consecutive cols (q*4+reg) per tile -> packed stores. 80 KB LDS.
__global__ __launch_bounds__(256) void sage_gemm(
    const float* __restrict__ x, unsigned char* __restrict__ ws)
{
  __shared__ __align__(16) unsigned char sW[65536];
  __shared__ __align__(16) unsigned char sX[16384];

  const int tid = threadIdx.x, lane = tid & 63, wid = tid >> 6;
  const int bid = xcd_swz_g(blockIdx.x);
  const int row0 = bid * 64;
  const int fl = lane & 15, q = lane >> 4;

  // ---- issue x loads FIRST (oldest in vmcnt FIFO)
  float4 xv[8];
#pragma unroll
  for (int j = 0; j < 8; ++j) {
    const int c = j * 256 + tid;        // 0..2047
    const int r = c >> 5, f4 = c & 31;
    xv[j] = *reinterpret_cast<const float4*>(x + (size_t)(row0 + r) * NF + f4 * 4);
  }
  // ---- stage full 64KB weight table into LDS (async DMA, linear dest)
#pragma unroll
  for (int i = 0; i < 16; ++i) {
    const int c0 = i * 256 + wid * 64;
    stage16(ws + (size_t)(c0 + lane) * 16, sW + (size_t)c0 * 16);
  }
  // ---- convert x -> bf16, write swizzled x-tile (waits only on xv loads)
#pragma unroll
  for (int j = 0; j < 8; ++j) {
    const int c = j * 256 + tid;
    const int r = c >> 5, f4 = c & 31;
    uint2 p;
    p.x = f2bf(xv[j].x) | (f2bf(xv[j].y) << 16);
    p.y = f2bf(xv[j].z) | (f2bf(xv[j].w) << 16);
    *reinterpret_cast<uint2*>(sX + swzx(r, f4 * 8)) = p;
  }
  __syncthreads();

  // ---- x B-fragments from LDS (16 rows per wave)
  bf16x8_t bx[4];
  const int xr = wid * 16 + fl;
#pragma unroll
  for (int s = 0; s < 4; ++s)
    bx[s] = *reinterpret_cast<const bf16x8_t*>(sX + swzx(xr, s * 64 + q * 16));

  // ---- 64 MFMA, weight frags streamed from LDS (compiler lgkmcnt-pipelined)
  f32x4_t acc[16];
#pragma unroll
  for (int t = 0; t < 16; ++t) acc[t] = (f32x4_t){0.f, 0.f, 0.f, 0.f};
  const bf16x8_t* sWf = reinterpret_cast<const bf16x8_t*>(sW);
#pragma unroll
  for (int t = 0; t < 16; ++t)
#pragma unroll
    for (int s = 0; s < 4; ++s)
      acc[t] = __builtin_amdgcn_mfma_f32_16x16x32_bf16(
          sWf[(t * 4 + s) * 64 + lane], bx[s], acc[t], 0, 0, 0);

  // ---- epilogue: packed stores
  const float* bias = reinterpret_cast<const float*>(ws + BIAS_OFF);
  const int myrow = row0 + wid * 16 + fl;
  unsigned short* sp = reinterpret_cast<unsigned short*>(ws + S_OFF);
#pragma unroll
  for (int t = 0; t < 8; ++t) {
    const int c4 = t * 16 + q * 4;
    const float4 b = *reinterpret_cast<const float4*>(bias + c4);
    uint2 p;
    p.x = f2bf(acc[t][0] + b.x) | (f2bf(acc[t][1] + b.y) << 16);
    p.y = f2bf(acc[t][2] + b.z) | (f2bf(acc[t][3] + b.w) << 16);
    *reinterpret_cast<uint2*>(sp + (size_t)myrow * NF + c4) = p;
  }
  unsigned char* yp = ws + Y_OFF;
#pragma unroll
  for (int t = 8; t < 16; ++t) {
    const int c4 = (t - 8) * 16 + q * 4;
    int w8 = __builtin_amdgcn_cvt_pk_fp8_f32(acc[t][0], acc[t][1], 0, false);
    w8 = __builtin_amdgcn_cvt_pk_fp8_f32(acc[t][2], acc[t][3], w8, true);
    *reinterpret_cast<unsigned int*>(yp + (size_t)myrow * NF + c4) =
        (unsigned int)w8;
  }
}

// ---------------- K3: out = relu(s + mean_k y[idx_k]), 16-deep MLP -------
__global__ __launch_bounds__(256) void sage_fin(
    const unsigned char* __restrict__ ws, const int* __restrict__ adj,
    float* __restrict__ out)
{
  const int tid = threadIdx.x, lane = tid & 63, wid = tid >> 6;
  const int bid = xcd_swz_f(blockIdx.x);
  const int rg = lane >> 4, fl = lane & 15;   // 4 rows/wave, 16 lanes/row
  const int row = bid * 16 + wid * 4 + rg;
  const int b = row / NNODE;

  const unsigned short* sp = reinterpret_cast<const unsigned short*>(ws + S_OFF);
  const unsigned char* yb = ws + Y_OFF + (size_t)b * NNODE * NF + fl * 8;

  const int4* a4 = reinterpret_cast<const int4*>(adj + (size_t)row * NK);
  const int4 t0 = a4[0], t1 = a4[1], t2 = a4[2], t3 = a4[3];
  const int idx[16] = {t0.x, t0.y, t0.z, t0.w, t1.x, t1.y, t1.z, t1.w,
                       t2.x, t2.y, t2.z, t2.w, t3.x, t3.y, t3.z, t3.w};

  const uint4 sv = *reinterpret_cast<const uint4*>(sp + (size_t)row * NF + fl * 8);

  uint2 v[16];
#pragma unroll
  for (int k = 0; k < 16; ++k)
    v[k] = *reinterpret_cast<const uint2*>(yb + (size_t)idx[k] * NF);
  __builtin_amdgcn_sched_barrier(0);   // pin: all 16 loads issue before use

  f32x2_t g0 = {0.f, 0.f}, g1 = {0.f, 0.f}, g2 = {0.f, 0.f}, g3 = {0.f, 0.f};
#pragma unroll
  for (int k = 0; k < 16; ++k) {
    g0 += __builtin_amdgcn_cvt_pk_f32_fp8(v[k].x, false);
    g1 += __builtin_amdgcn_cvt_pk_f32_fp8(v[k].x, true);
    g2 += __builtin_amdgcn_cvt_pk_f32_fp8(v[k].y, false);
    g3 += __builtin_amdgcn_cvt_pk_f32_fp8(v[k].y, true);
  }

  float se[8];
  se[0] = __uint_as_float(sv.x << 16); se[1] = __uint_as_float(sv.x & 0xffff0000u);
  se[2] = __uint_as_float(sv.y << 16); se[3] = __uint_as_float(sv.y & 0xffff0000u);
  se[4] = __uint_as_float(sv.z << 16); se[5] = __uint_as_float(sv.z & 0xffff0000u);
  se[6] = __uint_as_float(sv.w << 16); se[7] = __uint_as_float(sv.w & 0xffff0000u);

  const float sc = 1.f / 16.f;
  float4 o0, o1;
  o0.x = fmaxf(se[0] + g0[0] * sc, 0.f);
  o0.y = fmaxf(se[1] + g0[1] * sc, 0.f);
  o0.z = fmaxf(se[2] + g1[0] * sc, 0.f);
  o0.w = fmaxf(se[3] + g1[1] * sc, 0.f);
  o1.x = fmaxf(se[4] + g2[0] * sc, 0.f);
  o1.y = fmaxf(se[5] + g2[1] * sc, 0.f);
  o1.z = fmaxf(se[6] + g3[0] * sc, 0.f);
  o1.w = fmaxf(se[7] + g3[1] * sc, 0.f);
  float* op = out + (size_t)row * NF + fl * 8;
  *reinterpret_cast<float4*>(op)     = o0;
  *reinterpret_cast<float4*>(op + 4) = o1;
}

extern "C" void kernel_launch(void* const* d_in, const int* in_sizes, int n_in,
                              void* d_out, int out_size, void* d_ws, size_t ws_size,
                              hipStream_t stream) {
  const float* x     = (const float*)d_in[0];
  const int*   adj   = (const int*)d_in[1];
  const float* Wself = (const float*)d_in[2];
  const float* bself = (const float*)d_in[3];
  const float* Wnei  = (const float*)d_in[4];
  const float* bnei  = (const float*)d_in[5];
  float* out = (float*)d_out;
  unsigned char* ws = (unsigned char*)d_ws;

  hipLaunchKernelGGL(sage_wprep, dim3(17), dim3(256), 0, stream,
                     Wself, bself, Wnei, bnei, ws);
  hipLaunchKernelGGL(sage_gemm, dim3(NBLK_G), dim3(256), 0, stream, x, ws);
  hipLaunchKernelGGL(sage_fin, dim3(NBLK_F), dim3(256), 0, stream,
                     ws, adj, out);
}